// Round 1
// baseline (185.996 us; speedup 1.0000x reference)
//
#include <hip/hip_runtime.h>
#include <math.h>

// ---------------- problem constants ----------------
#define HH 224
#define NS 3000          // 30*100 samples
#define NF 147           // 3*7*7 encoder feats
#define ND 512
#define NSIG 49          // 7x7 shift classes

// ---------------- ws layout (float offsets) ----------------
// WT: float4[7*224] packed as (w0,w1,bitcast i0,bitcast i1)
#define OFF_WT     0            // 6272 floats (7*224*4)
#define OFF_FEATS  6272         // 147
#define OFF_HSTAR  6432         // 512
#define OFF_HSN    6944         // 1 (padded to 16)
#define OFF_V      6960         // 7*3*224*49 = 230496
#define OFF_T      237456       // 49*147*49 = 352947 (padded)
#define OFF_F      590416       // 3000*147 = 441000
#define OFF_NUM    1031416      // 3000
#define OFF_NRM    1034416      // 3000
#define OFF_G      1037416      // 3*2401 = 7203 (padded)
#define OFF_C      1044624      // 3*7*7*224 = 32928
// total = 1077552 floats = 4.31 MB

// weight of upsample(+reflect,+shift): output pixel p, shift sigma
__device__ __forceinline__ void wt_compute(int sigma, int p, int& i0c, int& i1c,
                                           float& w0, float& w1) {
  int k = p + sigma - 3;
  int r = k < 0 ? -k : (k > 223 ? 446 - k : k);   // np.pad 'reflect'
  float tc = (float)(2 * r - 31) * (1.0f / 64.0f); // (r+0.5)/32 - 0.5, exact
  float fl = floorf(tc);
  int i0 = (int)fl;
  float fr = tc - fl;
  i0c = min(max(i0, 0), 6);
  i1c = min(max(i0 + 1, 0), 6);
  w0 = 1.0f - fr;
  w1 = fr;
}

// blocks 0..146: h_star feats (32x32 block means); 147: weight table; 148: zero G
__global__ void __launch_bounds__(256) k_init(const float* __restrict__ x,
                                              float* __restrict__ ws) {
  int b = blockIdx.x;
  int t = threadIdx.x;
  if (b < NF) {
    int c = b / 49, rem = b % 49, cy = rem / 7, cx = rem % 7;
    float acc = 0.f;
    for (int idx = t; idx < 1024; idx += 256) {
      int yy = idx >> 5, xx = idx & 31;
      acc += x[(c * 224 + cy * 32 + yy) * 224 + cx * 32 + xx];
    }
    for (int off = 32; off; off >>= 1) acc += __shfl_down(acc, off);
    __shared__ float red[4];
    int wave = t >> 6, lane = t & 63;
    if (lane == 0) red[wave] = acc;
    __syncthreads();
    if (t == 0) ws[OFF_FEATS + b] = (red[0] + red[1] + red[2] + red[3]) * (1.0f / 1024.0f);
  } else if (b == NF) {
    float4* WT = (float4*)(ws + OFF_WT);
    for (int e = t; e < 7 * 224; e += 256) {
      int sigma = e / 224, p = e % 224;
      int i0c, i1c; float w0, w1;
      wt_compute(sigma, p, i0c, i1c, w0, w1);
      WT[e] = make_float4(w0, w1, __int_as_float(i0c), __int_as_float(i1c));
    }
  } else {
    for (int e = t; e < 3 * 2401; e += 256) ws[OFF_G + e] = 0.f;
  }
}

// h_star = feats @ Wenc, plus ||h_star||
__global__ void __launch_bounds__(512) k_hstar(const float* __restrict__ Wenc,
                                               float* __restrict__ ws) {
  __shared__ float sFeats[NF];
  __shared__ float red[8];
  int t = threadIdx.x;
  if (t < NF) sFeats[t] = ws[OFF_FEATS + t];
  __syncthreads();
  float h = 0.f;
  for (int f = 0; f < NF; ++f) h = fmaf(sFeats[f], Wenc[f * ND + t], h);
  ws[OFF_HSTAR + t] = h;
  float sq = h * h;
  for (int off = 32; off; off >>= 1) sq += __shfl_down(sq, off);
  int wave = t >> 6, lane = t & 63;
  if (lane == 0) red[wave] = sq;
  __syncthreads();
  if (t == 0) {
    float s = 0.f;
    #pragma unroll
    for (int w = 0; w < 8; ++w) s += red[w];
    ws[OFF_HSN] = sqrtf(s);
  }
}

// V[sy][c][y][cx][gx] = sum_{x in cx-block} wx(x,gx;sy) * img[c,y,x]
__global__ void __launch_bounds__(256) k_V(const float* __restrict__ x,
                                           float* __restrict__ ws) {
  int tid = blockIdx.x * blockDim.x + threadIdx.x;
  if (tid >= 7 * 3 * 224 * 7) return;
  int cx = tid % 7;
  int y  = (tid / 7) % 224;
  int c  = (tid / (7 * 224)) % 3;
  int sy = tid / (7 * 224 * 3);
  const float4* WT = (const float4*)(ws + OFF_WT);
  float acc[7];
  #pragma unroll
  for (int g = 0; g < 7; ++g) acc[g] = 0.f;
  const float* xrow = x + (c * 224 + y) * 224;
  for (int x0 = 0; x0 < 32; ++x0) {
    int px = cx * 32 + x0;
    float4 wt = WT[sy * 224 + px];
    int i0 = __float_as_int(wt.z), i1 = __float_as_int(wt.w);
    float v = xrow[px];
    #pragma unroll
    for (int g = 0; g < 7; ++g) {
      float w = (g == i0 ? wt.x : 0.f) + (g == i1 ? wt.y : 0.f);
      acc[g] = fmaf(w, v, acc[g]);
    }
  }
  float* Vp = ws + OFF_V + (((sy * 3 + c) * 224 + y) * 49 + cx * 7);
  #pragma unroll
  for (int g = 0; g < 7; ++g) Vp[g] = acc[g];
}

// T[sig][f][g] = (1/1024) sum_{y in cy-block} wy(y,gy;sx) * V[sy][c][y][cx][gx]
__global__ void __launch_bounds__(256) k_T(float* __restrict__ ws) {
  int tid = blockIdx.x * blockDim.x + threadIdx.x;
  if (tid >= NSIG * NF * 49) return;
  int g = tid % 49;
  int f = (tid / 49) % NF;
  int sig = tid / (49 * NF);
  int sx = sig / 7, sy = sig % 7;
  int gy = g / 7, gx = g % 7;
  int c = f / 49, rem = f % 49, cy = rem / 7, cx = rem % 7;
  const float4* WT = (const float4*)(ws + OFF_WT);
  const float* V = ws + OFF_V + ((sy * 3 + c) * 224) * 49 + cx * 7 + gx;
  float acc = 0.f;
  for (int y0 = 0; y0 < 32; ++y0) {
    int y = cy * 32 + y0;
    float4 wt = WT[sx * 224 + y];
    int i0 = __float_as_int(wt.z), i1 = __float_as_int(wt.w);
    float w = (gy == i0 ? wt.x : 0.f) + (gy == i1 ? wt.y : 0.f);
    acc = fmaf(w, V[y * 49], acc);
  }
  ws[OFF_T + tid] = acc * (1.0f / 1024.0f);
}

// F[i][f] = sum_g T[sig_i][f][g] * grid_i[g]   (one block per sample)
__global__ void __launch_bounds__(192) k_F(const float* __restrict__ grids,
                                           const int* __restrict__ shx,
                                           const int* __restrict__ shy,
                                           float* __restrict__ ws) {
  int i = blockIdx.x;
  __shared__ float sg[49];
  __shared__ int ssig;
  int t = threadIdx.x;
  if (t < 49) sg[t] = grids[i * 49 + t];
  if (t == 0) ssig = shx[i] * 7 + shy[i];
  __syncthreads();
  if (t < NF) {
    const float* Trow = ws + OFF_T + (ssig * NF + t) * 49;
    float acc = 0.f;
    #pragma unroll
    for (int g = 0; g < 49; ++g) acc = fmaf(Trow[g], sg[g], acc);
    ws[OFF_F + i * NF + t] = acc;
  }
}

// fused H = F @ Wenc with per-row reduction to num = h.h*, nrm = h.h (8 rows/block)
__global__ void __launch_bounds__(256) k_H(const float* __restrict__ Wenc,
                                           float* __restrict__ ws) {
  __shared__ __align__(16) float sF[NF * 8];
  __shared__ float sHs[ND];
  __shared__ float sRed[2][8][4];
  int t = threadIdx.x;
  int i0 = blockIdx.x * 8;
  for (int idx = t; idx < NF * 8; idx += 256) {
    int f = idx >> 3, r = idx & 7;
    sF[idx] = ws[OFF_F + (i0 + r) * NF + f];
  }
  sHs[t] = ws[OFF_HSTAR + t];
  sHs[t + 256] = ws[OFF_HSTAR + t + 256];
  __syncthreads();
  float accA[8], accB[8];
  #pragma unroll
  for (int r = 0; r < 8; ++r) { accA[r] = 0.f; accB[r] = 0.f; }
  const float* W0 = Wenc + t;
  const float* W1 = Wenc + t + 256;
  const float4* sF4 = (const float4*)sF;
  for (int f = 0; f < NF; ++f) {
    float w0 = W0[f * ND];
    float w1 = W1[f * ND];
    float4 aLo = sF4[f * 2];
    float4 aHi = sF4[f * 2 + 1];
    float a[8] = {aLo.x, aLo.y, aLo.z, aLo.w, aHi.x, aHi.y, aHi.z, aHi.w};
    #pragma unroll
    for (int r = 0; r < 8; ++r) {
      accA[r] = fmaf(a[r], w0, accA[r]);
      accB[r] = fmaf(a[r], w1, accB[r]);
    }
  }
  float hs0 = sHs[t], hs1 = sHs[t + 256];
  int wave = t >> 6, lane = t & 63;
  #pragma unroll
  for (int r = 0; r < 8; ++r) {
    float np = accA[r] * hs0 + accB[r] * hs1;
    float sp = accA[r] * accA[r] + accB[r] * accB[r];
    for (int off = 32; off; off >>= 1) {
      np += __shfl_down(np, off);
      sp += __shfl_down(sp, off);
    }
    if (lane == 0) { sRed[0][r][wave] = np; sRed[1][r][wave] = sp; }
  }
  __syncthreads();
  if (t < 8) {
    float np = sRed[0][t][0] + sRed[0][t][1] + sRed[0][t][2] + sRed[0][t][3];
    float sp = sRed[1][t][0] + sRed[1][t][1] + sRed[1][t][2] + sRed[1][t][3];
    ws[OFF_NUM + i0 + t] = np;
    ws[OFF_NRM + i0 + t] = sp;
  }
}

// s_i, then class-accumulate G_k[sig][g] = sum s^k * grid
__global__ void __launch_bounds__(256) k_G(const float* __restrict__ grids,
                                           const int* __restrict__ shx,
                                           const int* __restrict__ shy,
                                           float* __restrict__ ws) {
  int i = blockIdx.x * blockDim.x + threadIdx.x;
  if (i >= NS) return;
  float num = ws[OFF_NUM + i], nrm = ws[OFF_NRM + i];
  float hsn = ws[OFF_HSN];
  float den = fmaxf(hsn * sqrtf(nrm), 1e-8f);
  float s = num / den;
  float s2 = s * s;
  int sig = shx[i] * 7 + shy[i];
  float* G0 = ws + OFF_G + sig * 49;
  const float* g = grids + i * 49;
  for (int k = 0; k < 49; ++k) {
    float gv = g[k];
    if (gv != 0.f) {
      atomicAdd(&G0[k], gv);
      atomicAdd(&G0[2401 + k], gv * s);
      atomicAdd(&G0[4802 + k], gv * s2);
    }
  }
}

// C_k[sx][gy][px] = sum_{sy,gx} wx(px,gx;sy) * G_k[sx,sy][gy,gx]
__global__ void __launch_bounds__(256) k_C(float* __restrict__ ws) {
  int tid = blockIdx.x * blockDim.x + threadIdx.x;
  if (tid >= 7 * 7 * 224) return;
  int px = tid % 224;
  int gy = (tid / 224) % 7;
  int sx = tid / (224 * 7);
  const float4* WT = (const float4*)(ws + OFF_WT);
  const float* G = ws + OFF_G;
  float c0 = 0.f, c1 = 0.f, c2 = 0.f;
  for (int sy = 0; sy < 7; ++sy) {
    float4 wt = WT[sy * 224 + px];
    int i0 = __float_as_int(wt.z), i1 = __float_as_int(wt.w);
    int base = (sx * 7 + sy) * 49 + gy * 7;
    c0 += wt.x * G[base + i0] + wt.y * G[base + i1];
    c1 += wt.x * G[2401 + base + i0] + wt.y * G[2401 + base + i1];
    c2 += wt.x * G[4802 + base + i0] + wt.y * G[4802 + base + i1];
  }
  float* C = ws + OFF_C;
  int cidx = (sx * 7 + gy) * 224 + px;
  C[cidx] = c0;
  C[10976 + cidx] = c1;
  C[21952 + cidx] = c2;
}

// final: S_k(py,px) = sum_{sx,gy} wy(py,gy;sx) * C_k[sx][gy][px]; Welford closed form
__global__ void __launch_bounds__(256) k_out(const float* __restrict__ ws,
                                             float* __restrict__ out) {
  int tid = blockIdx.x * blockDim.x + threadIdx.x;
  if (tid >= 224 * 224) return;
  int px = tid % 224, py = tid / 224;
  const float4* WT = (const float4*)(ws + OFF_WT);
  const float* C = ws + OFF_C;
  float S0 = 0.f, S1 = 0.f, S2 = 0.f;
  for (int sx = 0; sx < 7; ++sx) {
    float4 wt = WT[sx * 224 + py];
    int i0 = __float_as_int(wt.z), i1 = __float_as_int(wt.w);
    int b0 = (sx * 7 + i0) * 224 + px;
    int b1 = (sx * 7 + i1) * 224 + px;
    S0 += wt.x * C[b0] + wt.y * C[b1];
    S1 += wt.x * C[10976 + b0] + wt.y * C[10976 + b1];
    S2 += wt.x * C[21952 + b0] + wt.y * C[21952 + b1];
  }
  float W = 1e-10f + S0;            // sow (includes init pseudo-weight)
  float R = S1 / W;                 // importance
  float U = S2 - S1 * S1 / W;       // weighted sum of squared deviations
  float unc = U / (W - 1.0f);
  out[tid] = R;
  out[224 * 224 + tid] = unc;
}

extern "C" void kernel_launch(void* const* d_in, const int* in_sizes, int n_in,
                              void* d_out, int out_size, void* d_ws, size_t ws_size,
                              hipStream_t stream) {
  const float* x     = (const float*)d_in[0];
  const float* Wenc  = (const float*)d_in[1];
  const float* grids = (const float*)d_in[2];
  const int*   shx   = (const int*)d_in[3];
  const int*   shy   = (const int*)d_in[4];
  float* out = (float*)d_out;
  float* ws  = (float*)d_ws;

  k_init<<<149, 256, 0, stream>>>(x, ws);
  k_hstar<<<1, 512, 0, stream>>>(Wenc, ws);
  k_V<<<(7 * 3 * 224 * 7 + 255) / 256, 256, 0, stream>>>(x, ws);
  k_T<<<(NSIG * NF * 49 + 255) / 256, 256, 0, stream>>>(ws);
  k_F<<<NS, 192, 0, stream>>>(grids, shx, shy, ws);
  k_H<<<NS / 8, 256, 0, stream>>>(Wenc, ws);
  k_G<<<(NS + 255) / 256, 256, 0, stream>>>(grids, shx, shy, ws);
  k_C<<<(7 * 7 * 224 + 255) / 256, 256, 0, stream>>>(ws);
  k_out<<<(224 * 224 + 255) / 256, 256, 0, stream>>>(ws, out);
}

// Round 2
// 149.815 us; speedup vs baseline: 1.2415x; 1.2415x over previous
//
#include <hip/hip_runtime.h>
#include <math.h>

// ---------------- problem constants ----------------
#define HH 224
#define NS 3000          // 30*100 samples
#define NF 147           // 3*7*7 encoder feats
#define ND 512
#define NSIG 49          // 7x7 shift classes
#define NGBLK 30         // blocks for k_G partials
#define GSTRIDE 7232     // padded 3*2401

// ---------------- ws layout (float offsets) ----------------
// WT: float4[7*224] packed as (w0,w1,bitcast i0,bitcast i1)
#define OFF_WT     0            // 6272 floats (7*224*4)
#define OFF_FEATS  6272         // 147
#define OFF_HSTAR  6432         // 512
#define OFF_HSN    6944         // 1 (padded to 16)
#define OFF_V      6960         // 7*3*224*49 = 230496
#define OFF_T      237456       // 49*147*49 = 352947 (padded)
#define OFF_F      590416       // 3000*147 = 441000
#define OFF_NUM    1031416      // 3000
#define OFF_NRM    1034416      // 3000
#define OFF_G      1037416      // 3*2401 = 7203 (padded)
#define OFF_C      1044624      // 3*7*7*224 = 32928
// G partials reuse the dead F region after k_H has consumed it:
#define OFF_GP     OFF_F        // 30*7232 = 216960 < 441000 (fits in F)
// total = 1077552 floats = 4.31 MB

// weight of upsample(+reflect,+shift): output pixel p, shift sigma
__device__ __forceinline__ void wt_compute(int sigma, int p, int& i0c, int& i1c,
                                           float& w0, float& w1) {
  int k = p + sigma - 3;
  int r = k < 0 ? -k : (k > 223 ? 446 - k : k);   // np.pad 'reflect'
  float tc = (float)(2 * r - 31) * (1.0f / 64.0f); // (r+0.5)/32 - 0.5, exact
  float fl = floorf(tc);
  int i0 = (int)fl;
  float fr = tc - fl;
  i0c = min(max(i0, 0), 6);
  i1c = min(max(i0 + 1, 0), 6);
  w0 = 1.0f - fr;
  w1 = fr;
}

// blocks 0..146: h_star feats (32x32 block means); 147: weight table
__global__ void __launch_bounds__(256) k_init(const float* __restrict__ x,
                                              float* __restrict__ ws) {
  int b = blockIdx.x;
  int t = threadIdx.x;
  if (b < NF) {
    int c = b / 49, rem = b % 49, cy = rem / 7, cx = rem % 7;
    float acc = 0.f;
    for (int idx = t; idx < 1024; idx += 256) {
      int yy = idx >> 5, xx = idx & 31;
      acc += x[(c * 224 + cy * 32 + yy) * 224 + cx * 32 + xx];
    }
    for (int off = 32; off; off >>= 1) acc += __shfl_down(acc, off);
    __shared__ float red[4];
    int wave = t >> 6, lane = t & 63;
    if (lane == 0) red[wave] = acc;
    __syncthreads();
    if (t == 0) ws[OFF_FEATS + b] = (red[0] + red[1] + red[2] + red[3]) * (1.0f / 1024.0f);
  } else {
    float4* WT = (float4*)(ws + OFF_WT);
    for (int e = t; e < 7 * 224; e += 256) {
      int sigma = e / 224, p = e % 224;
      int i0c, i1c; float w0, w1;
      wt_compute(sigma, p, i0c, i1c, w0, w1);
      WT[e] = make_float4(w0, w1, __int_as_float(i0c), __int_as_float(i1c));
    }
  }
}

// h_star = feats @ Wenc, plus ||h_star||
__global__ void __launch_bounds__(512) k_hstar(const float* __restrict__ Wenc,
                                               float* __restrict__ ws) {
  __shared__ float sFeats[NF];
  __shared__ float red[8];
  int t = threadIdx.x;
  if (t < NF) sFeats[t] = ws[OFF_FEATS + t];
  __syncthreads();
  float h = 0.f;
  for (int f = 0; f < NF; ++f) h = fmaf(sFeats[f], Wenc[f * ND + t], h);
  ws[OFF_HSTAR + t] = h;
  float sq = h * h;
  for (int off = 32; off; off >>= 1) sq += __shfl_down(sq, off);
  int wave = t >> 6, lane = t & 63;
  if (lane == 0) red[wave] = sq;
  __syncthreads();
  if (t == 0) {
    float s = 0.f;
    #pragma unroll
    for (int w = 0; w < 8; ++w) s += red[w];
    ws[OFF_HSN] = sqrtf(s);
  }
}

// V[sy][c][y][cx][gx] = sum_{x in cx-block} wx(x,gx;sy) * img[c,y,x]
__global__ void __launch_bounds__(256) k_V(const float* __restrict__ x,
                                           float* __restrict__ ws) {
  int tid = blockIdx.x * blockDim.x + threadIdx.x;
  if (tid >= 7 * 3 * 224 * 7) return;
  int cx = tid % 7;
  int y  = (tid / 7) % 224;
  int c  = (tid / (7 * 224)) % 3;
  int sy = tid / (7 * 224 * 3);
  const float4* WT = (const float4*)(ws + OFF_WT);
  float acc[7];
  #pragma unroll
  for (int g = 0; g < 7; ++g) acc[g] = 0.f;
  const float* xrow = x + (c * 224 + y) * 224;
  for (int x0 = 0; x0 < 32; ++x0) {
    int px = cx * 32 + x0;
    float4 wt = WT[sy * 224 + px];
    int i0 = __float_as_int(wt.z), i1 = __float_as_int(wt.w);
    float v = xrow[px];
    #pragma unroll
    for (int g = 0; g < 7; ++g) {
      float w = (g == i0 ? wt.x : 0.f) + (g == i1 ? wt.y : 0.f);
      acc[g] = fmaf(w, v, acc[g]);
    }
  }
  float* Vp = ws + OFF_V + (((sy * 3 + c) * 224 + y) * 49 + cx * 7);
  #pragma unroll
  for (int g = 0; g < 7; ++g) Vp[g] = acc[g];
}

// T[sig][f][g] = (1/1024) sum_{y in cy-block} wy(y,gy;sx) * V[sy][c][y][cx][gx]
__global__ void __launch_bounds__(256) k_T(float* __restrict__ ws) {
  int tid = blockIdx.x * blockDim.x + threadIdx.x;
  if (tid >= NSIG * NF * 49) return;
  int g = tid % 49;
  int f = (tid / 49) % NF;
  int sig = tid / (49 * NF);
  int sx = sig / 7, sy = sig % 7;
  int gy = g / 7, gx = g % 7;
  int c = f / 49, rem = f % 49, cy = rem / 7, cx = rem % 7;
  const float4* WT = (const float4*)(ws + OFF_WT);
  const float* V = ws + OFF_V + ((sy * 3 + c) * 224) * 49 + cx * 7 + gx;
  float acc = 0.f;
  for (int y0 = 0; y0 < 32; ++y0) {
    int y = cy * 32 + y0;
    float4 wt = WT[sx * 224 + y];
    int i0 = __float_as_int(wt.z), i1 = __float_as_int(wt.w);
    float w = (gy == i0 ? wt.x : 0.f) + (gy == i1 ? wt.y : 0.f);
    acc = fmaf(w, V[y * 49], acc);
  }
  ws[OFF_T + tid] = acc * (1.0f / 1024.0f);
}

// F[i][f] = sum_g T[sig_i][f][g] * grid_i[g]   (one block per sample)
__global__ void __launch_bounds__(192) k_F(const float* __restrict__ grids,
                                           const int* __restrict__ shx,
                                           const int* __restrict__ shy,
                                           float* __restrict__ ws) {
  int i = blockIdx.x;
  __shared__ float sg[49];
  __shared__ int ssig;
  int t = threadIdx.x;
  if (t < 49) sg[t] = grids[i * 49 + t];
  if (t == 0) ssig = shx[i] * 7 + shy[i];
  __syncthreads();
  if (t < NF) {
    const float* Trow = ws + OFF_T + (ssig * NF + t) * 49;
    float acc = 0.f;
    #pragma unroll
    for (int g = 0; g < 49; ++g) acc = fmaf(Trow[g], sg[g], acc);
    ws[OFF_F + i * NF + t] = acc;
  }
}

// fused H = F @ Wenc with per-row reduction to num = h.h*, nrm = h.h (8 rows/block)
__global__ void __launch_bounds__(256) k_H(const float* __restrict__ Wenc,
                                           float* __restrict__ ws) {
  __shared__ __align__(16) float sF[NF * 8];
  __shared__ float sHs[ND];
  __shared__ float sRed[2][8][4];
  int t = threadIdx.x;
  int i0 = blockIdx.x * 8;
  for (int idx = t; idx < NF * 8; idx += 256) {
    int f = idx >> 3, r = idx & 7;
    sF[idx] = ws[OFF_F + (i0 + r) * NF + f];
  }
  sHs[t] = ws[OFF_HSTAR + t];
  sHs[t + 256] = ws[OFF_HSTAR + t + 256];
  __syncthreads();
  float accA[8], accB[8];
  #pragma unroll
  for (int r = 0; r < 8; ++r) { accA[r] = 0.f; accB[r] = 0.f; }
  const float* W0 = Wenc + t;
  const float* W1 = Wenc + t + 256;
  const float4* sF4 = (const float4*)sF;
  for (int f = 0; f < NF; ++f) {
    float w0 = W0[f * ND];
    float w1 = W1[f * ND];
    float4 aLo = sF4[f * 2];
    float4 aHi = sF4[f * 2 + 1];
    float a[8] = {aLo.x, aLo.y, aLo.z, aLo.w, aHi.x, aHi.y, aHi.z, aHi.w};
    #pragma unroll
    for (int r = 0; r < 8; ++r) {
      accA[r] = fmaf(a[r], w0, accA[r]);
      accB[r] = fmaf(a[r], w1, accB[r]);
    }
  }
  float hs0 = sHs[t], hs1 = sHs[t + 256];
  int wave = t >> 6, lane = t & 63;
  #pragma unroll
  for (int r = 0; r < 8; ++r) {
    float np = accA[r] * hs0 + accB[r] * hs1;
    float sp = accA[r] * accA[r] + accB[r] * accB[r];
    for (int off = 32; off; off >>= 1) {
      np += __shfl_down(np, off);
      sp += __shfl_down(sp, off);
    }
    if (lane == 0) { sRed[0][r][wave] = np; sRed[1][r][wave] = sp; }
  }
  __syncthreads();
  if (t < 8) {
    float np = sRed[0][t][0] + sRed[0][t][1] + sRed[0][t][2] + sRed[0][t][3];
    float sp = sRed[1][t][0] + sRed[1][t][1] + sRed[1][t][2] + sRed[1][t][3];
    ws[OFF_NUM + i0 + t] = np;
    ws[OFF_NRM + i0 + t] = sp;
  }
}

// s_i, then per-block LDS class-accumulate; partial G per block (no global atomics)
__global__ void __launch_bounds__(256) k_G(const float* __restrict__ grids,
                                           const int* __restrict__ shx,
                                           const int* __restrict__ shy,
                                           float* __restrict__ ws) {
  __shared__ float sG[3 * 2401];
  int b = blockIdx.x;
  int t = threadIdx.x;
  for (int e = t; e < 3 * 2401; e += 256) sG[e] = 0.f;
  __syncthreads();
  if (t < 100) {
    int i = b * 100 + t;
    float num = ws[OFF_NUM + i], nrm = ws[OFF_NRM + i];
    float hsn = ws[OFF_HSN];
    float den = fmaxf(hsn * sqrtf(nrm), 1e-8f);
    float s = num / den;
    float s2 = s * s;
    int sig = shx[i] * 7 + shy[i];
    float* B0 = sG + sig * 49;
    const float* g = grids + i * 49;
    for (int k = 0; k < 49; ++k) {
      if (g[k] != 0.f) {
        atomicAdd(&B0[k], 1.0f);
        atomicAdd(&B0[2401 + k], s);
        atomicAdd(&B0[4802 + k], s2);
      }
    }
  }
  __syncthreads();
  float* P = ws + OFF_GP + b * GSTRIDE;
  for (int e = t; e < 3 * 2401; e += 256) P[e] = sG[e];
}

// sum the 30 per-block partials into G
__global__ void __launch_bounds__(256) k_Gsum(float* __restrict__ ws) {
  int e = blockIdx.x * 256 + threadIdx.x;
  if (e >= 3 * 2401) return;
  float acc = 0.f;
  for (int b = 0; b < NGBLK; ++b) acc += ws[OFF_GP + b * GSTRIDE + e];
  ws[OFF_G + e] = acc;
}

// C_k[sx][gy][px] = sum_{sy,gx} wx(px,gx;sy) * G_k[sx,sy][gy,gx]
__global__ void __launch_bounds__(256) k_C(float* __restrict__ ws) {
  int tid = blockIdx.x * blockDim.x + threadIdx.x;
  if (tid >= 7 * 7 * 224) return;
  int px = tid % 224;
  int gy = (tid / 224) % 7;
  int sx = tid / (224 * 7);
  const float4* WT = (const float4*)(ws + OFF_WT);
  const float* G = ws + OFF_G;
  float c0 = 0.f, c1 = 0.f, c2 = 0.f;
  for (int sy = 0; sy < 7; ++sy) {
    float4 wt = WT[sy * 224 + px];
    int i0 = __float_as_int(wt.z), i1 = __float_as_int(wt.w);
    int base = (sx * 7 + sy) * 49 + gy * 7;
    c0 += wt.x * G[base + i0] + wt.y * G[base + i1];
    c1 += wt.x * G[2401 + base + i0] + wt.y * G[2401 + base + i1];
    c2 += wt.x * G[4802 + base + i0] + wt.y * G[4802 + base + i1];
  }
  float* C = ws + OFF_C;
  int cidx = (sx * 7 + gy) * 224 + px;
  C[cidx] = c0;
  C[10976 + cidx] = c1;
  C[21952 + cidx] = c2;
}

// final: S_k(py,px) = sum_{sx,gy} wy(py,gy;sx) * C_k[sx][gy][px]; Welford closed form
__global__ void __launch_bounds__(256) k_out(const float* __restrict__ ws,
                                             float* __restrict__ out) {
  int tid = blockIdx.x * blockDim.x + threadIdx.x;
  if (tid >= 224 * 224) return;
  int px = tid % 224, py = tid / 224;
  const float4* WT = (const float4*)(ws + OFF_WT);
  const float* C = ws + OFF_C;
  float S0 = 0.f, S1 = 0.f, S2 = 0.f;
  for (int sx = 0; sx < 7; ++sx) {
    float4 wt = WT[sx * 224 + py];
    int i0 = __float_as_int(wt.z), i1 = __float_as_int(wt.w);
    int b0 = (sx * 7 + i0) * 224 + px;
    int b1 = (sx * 7 + i1) * 224 + px;
    S0 += wt.x * C[b0] + wt.y * C[b1];
    S1 += wt.x * C[10976 + b0] + wt.y * C[10976 + b1];
    S2 += wt.x * C[21952 + b0] + wt.y * C[21952 + b1];
  }
  float W = 1e-10f + S0;            // sow (includes init pseudo-weight)
  float R = S1 / W;                 // importance
  float U = S2 - S1 * S1 / W;       // weighted sum of squared deviations
  float unc = U / (W - 1.0f);
  out[tid] = R;
  out[224 * 224 + tid] = unc;
}

extern "C" void kernel_launch(void* const* d_in, const int* in_sizes, int n_in,
                              void* d_out, int out_size, void* d_ws, size_t ws_size,
                              hipStream_t stream) {
  const float* x     = (const float*)d_in[0];
  const float* Wenc  = (const float*)d_in[1];
  const float* grids = (const float*)d_in[2];
  const int*   shx   = (const int*)d_in[3];
  const int*   shy   = (const int*)d_in[4];
  float* out = (float*)d_out;
  float* ws  = (float*)d_ws;

  k_init<<<148, 256, 0, stream>>>(x, ws);
  k_hstar<<<1, 512, 0, stream>>>(Wenc, ws);
  k_V<<<(7 * 3 * 224 * 7 + 255) / 256, 256, 0, stream>>>(x, ws);
  k_T<<<(NSIG * NF * 49 + 255) / 256, 256, 0, stream>>>(ws);
  k_F<<<NS, 192, 0, stream>>>(grids, shx, shy, ws);
  k_H<<<NS / 8, 256, 0, stream>>>(Wenc, ws);
  k_G<<<NGBLK, 256, 0, stream>>>(grids, shx, shy, ws);
  k_Gsum<<<(3 * 2401 + 255) / 256, 256, 0, stream>>>(ws);
  k_C<<<(7 * 7 * 224 + 255) / 256, 256, 0, stream>>>(ws);
  k_out<<<(224 * 224 + 255) / 256, 256, 0, stream>>>(ws, out);
}

// Round 3
// 136.919 us; speedup vs baseline: 1.3584x; 1.0942x over previous
//
#include <hip/hip_runtime.h>
#include <math.h>

// ---------------- problem constants ----------------
#define HH 224
#define NS 3000          // 30*100 samples
#define NF 147           // 3*7*7 encoder feats
#define ND 512
#define NSIG 49          // 7x7 shift classes
#define NGBLK 30         // blocks for k_G partials
#define GSTRIDE 7232     // padded 3*2401
#define NSAMP 12         // samples per k_H2 block
#define NHBLK 250        // 3000 / 12

// ---------------- ws layout (float offsets) ----------------
// WT: float4[7*224] packed as (w0,w1,bitcast i0,bitcast i1)
#define OFF_WT     0            // 6272 floats (7*224*4)
#define OFF_FEATS  6272         // 147
#define OFF_HSN    6944         // 1
#define OFF_V      6960         // 7*3*224*49 = 230496
#define OFF_T      237456       // T2[sig][g][f]: 49*49*147 = 352947
#define OFF_GP     590416       // 30*7232 = 216960 (k_G partials)
#define OFF_NUM    1031416      // 3000
#define OFF_NRM    1034416      // 3000
#define OFF_G      1037416      // 3*2401 = 7203 (padded)
#define OFF_C      1044624      // 3*7*7*224 = 32928
// total < 1077552 floats = 4.31 MB

// weight of upsample(+reflect,+shift): output pixel p, shift sigma
__device__ __forceinline__ void wt_compute(int sigma, int p, int& i0c, int& i1c,
                                           float& w0, float& w1) {
  int k = p + sigma - 3;
  int r = k < 0 ? -k : (k > 223 ? 446 - k : k);    // np.pad 'reflect'
  float tc = (float)(2 * r - 31) * (1.0f / 64.0f); // (r+0.5)/32 - 0.5, exact
  float fl = floorf(tc);
  int i0 = (int)fl;
  float fr = tc - fl;
  i0c = min(max(i0, 0), 6);
  i1c = min(max(i0 + 1, 0), 6);
  w0 = 1.0f - fr;
  w1 = fr;
}

// blocks 0..146: h_star feats (32x32 block means); 147: WT table; 148+: k_V work
// V[sy][c][y][cx][gx] = sum_{x in cx-block} wx(x,gx;sy) * img[c,y,x]
__global__ void __launch_bounds__(256) k_initV(const float* __restrict__ x,
                                               float* __restrict__ ws) {
  int b = blockIdx.x;
  int t = threadIdx.x;
  if (b < NF) {
    int c = b / 49, rem = b % 49, cy = rem / 7, cx = rem % 7;
    float acc = 0.f;
    for (int idx = t; idx < 1024; idx += 256) {
      int yy = idx >> 5, xx = idx & 31;
      acc += x[(c * 224 + cy * 32 + yy) * 224 + cx * 32 + xx];
    }
    for (int off = 32; off; off >>= 1) acc += __shfl_down(acc, off);
    __shared__ float red[4];
    int wave = t >> 6, lane = t & 63;
    if (lane == 0) red[wave] = acc;
    __syncthreads();
    if (t == 0) ws[OFF_FEATS + b] = (red[0] + red[1] + red[2] + red[3]) * (1.0f / 1024.0f);
  } else if (b == NF) {
    float4* WT = (float4*)(ws + OFF_WT);
    for (int e = t; e < 7 * 224; e += 256) {
      int sigma = e / 224, p = e % 224;
      int i0c, i1c; float w0, w1;
      wt_compute(sigma, p, i0c, i1c, w0, w1);
      WT[e] = make_float4(w0, w1, __int_as_float(i0c), __int_as_float(i1c));
    }
  } else {
    int tid = (b - NF - 1) * 256 + t;
    if (tid >= 7 * 3 * 224 * 7) return;
    int cx = tid % 7;
    int y  = (tid / 7) % 224;
    int c  = (tid / (7 * 224)) % 3;
    int sy = tid / (7 * 224 * 3);
    float acc[7];
    #pragma unroll
    for (int g = 0; g < 7; ++g) acc[g] = 0.f;
    const float* xrow = x + (c * 224 + y) * 224;
    for (int x0 = 0; x0 < 32; ++x0) {
      int px = cx * 32 + x0;
      int i0, i1; float w0, w1;
      wt_compute(sy, px, i0, i1, w0, w1);   // inline (no dep on WT block)
      float v = xrow[px];
      #pragma unroll
      for (int g = 0; g < 7; ++g) {
        float w = (g == i0 ? w0 : 0.f) + (g == i1 ? w1 : 0.f);
        acc[g] = fmaf(w, v, acc[g]);
      }
    }
    float* Vp = ws + OFF_V + (((sy * 3 + c) * 224 + y) * 49 + cx * 7);
    #pragma unroll
    for (int g = 0; g < 7; ++g) Vp[g] = acc[g];
  }
}

// T2[sig][g][f] = (1/1024) sum_{y in cy-block} wy(y,gy;sx) * V[sy][c][y][cx][gx]
// (transposed store so k_H2's f-varying lanes read consecutive addresses)
__global__ void __launch_bounds__(256) k_T(float* __restrict__ ws) {
  int tid = blockIdx.x * blockDim.x + threadIdx.x;
  if (tid >= NSIG * NF * 49) return;
  int g = tid % 49;
  int f = (tid / 49) % NF;
  int sig = tid / (49 * NF);
  int sx = sig / 7, sy = sig % 7;
  int gy = g / 7, gx = g % 7;
  int c = f / 49, rem = f % 49, cy = rem / 7, cx = rem % 7;
  const float4* WT = (const float4*)(ws + OFF_WT);
  const float* V = ws + OFF_V + ((sy * 3 + c) * 224) * 49 + cx * 7 + gx;
  float acc = 0.f;
  for (int y0 = 0; y0 < 32; ++y0) {
    int y = cy * 32 + y0;
    float4 wt = WT[sx * 224 + y];
    int i0 = __float_as_int(wt.z), i1 = __float_as_int(wt.w);
    float w = (gy == i0 ? wt.x : 0.f) + (gy == i1 ? wt.y : 0.f);
    acc = fmaf(w, V[y * 49], acc);
  }
  ws[OFF_T + (sig * 49 + g) * NF + f] = acc * (1.0f / 1024.0f);
}

// fused: F = T2[sig] @ g (in LDS), h_star col + H = F @ Wenc in one Wenc pass,
// per-row reduction to num = h.h*, nrm = h.h; also ||h*|| (identical per block)
__global__ void __launch_bounds__(256) k_H2(const float* __restrict__ Wenc,
                                            const float* __restrict__ grids,
                                            const int* __restrict__ shx,
                                            const int* __restrict__ shy,
                                            float* __restrict__ ws) {
  __shared__ __align__(16) float sF[NF * NSAMP];  // [f][r]
  __shared__ float sGr[NSAMP * 49];               // [r][g]
  __shared__ float sFeats[NF];
  __shared__ int   sSig[NSAMP];
  __shared__ float sRed[2][NSAMP][4];
  __shared__ float sRedH[4];
  int t = threadIdx.x;
  int i0s = blockIdx.x * NSAMP;
  for (int e = t; e < NSAMP * 49; e += 256) sGr[e] = grids[i0s * 49 + e];
  if (t < NSAMP) sSig[t] = shx[i0s + t] * 7 + shy[i0s + t];
  if (t < NF) sFeats[t] = ws[OFF_FEATS + t];
  __syncthreads();
  // F[r][f] = sum_g T2[sig_r][g][f] * grid_r[g]  (coalesced T2 reads)
  for (int idx = t; idx < NF * NSAMP; idx += 256) {
    int r = idx / NF, f = idx - r * NF;
    const float* T2 = ws + OFF_T + sSig[r] * (49 * NF) + f;
    const float* gr = sGr + r * 49;
    float acc = 0.f;
    #pragma unroll
    for (int g = 0; g < 49; ++g) acc = fmaf(T2[g * NF], gr[g], acc);
    sF[f * NSAMP + r] = acc;
  }
  __syncthreads();
  float accA[NSAMP], accB[NSAMP];
  #pragma unroll
  for (int r = 0; r < NSAMP; ++r) { accA[r] = 0.f; accB[r] = 0.f; }
  float h0 = 0.f, h1 = 0.f;
  const float* W0 = Wenc + t;
  const float* W1 = Wenc + t + 256;
  const float4* sF4 = (const float4*)sF;
  for (int f = 0; f < NF; ++f) {
    float w0 = W0[f * ND];
    float w1 = W1[f * ND];
    float fe = sFeats[f];
    h0 = fmaf(fe, w0, h0);
    h1 = fmaf(fe, w1, h1);
    float4 a0 = sF4[f * 3], a1 = sF4[f * 3 + 1], a2 = sF4[f * 3 + 2];
    float a[NSAMP] = {a0.x, a0.y, a0.z, a0.w, a1.x, a1.y, a1.z, a1.w,
                      a2.x, a2.y, a2.z, a2.w};
    #pragma unroll
    for (int r = 0; r < NSAMP; ++r) {
      accA[r] = fmaf(a[r], w0, accA[r]);
      accB[r] = fmaf(a[r], w1, accB[r]);
    }
  }
  int wave = t >> 6, lane = t & 63;
  float hq = h0 * h0 + h1 * h1;
  for (int off = 32; off; off >>= 1) hq += __shfl_down(hq, off);
  if (lane == 0) sRedH[wave] = hq;
  #pragma unroll
  for (int r = 0; r < NSAMP; ++r) {
    float np = accA[r] * h0 + accB[r] * h1;
    float sp = accA[r] * accA[r] + accB[r] * accB[r];
    for (int off = 32; off; off >>= 1) {
      np += __shfl_down(np, off);
      sp += __shfl_down(sp, off);
    }
    if (lane == 0) { sRed[0][r][wave] = np; sRed[1][r][wave] = sp; }
  }
  __syncthreads();
  if (t < NSAMP) {
    float np = sRed[0][t][0] + sRed[0][t][1] + sRed[0][t][2] + sRed[0][t][3];
    float sp = sRed[1][t][0] + sRed[1][t][1] + sRed[1][t][2] + sRed[1][t][3];
    ws[OFF_NUM + i0s + t] = np;
    ws[OFF_NRM + i0s + t] = sp;
  }
  if (t == 0) {
    // identical value from every block (same inputs, same order) -> benign race
    ws[OFF_HSN] = sqrtf(sRedH[0] + sRedH[1] + sRedH[2] + sRedH[3]);
  }
}

// s_i, then per-block LDS class-accumulate; partial G per block
__global__ void __launch_bounds__(256) k_G(const float* __restrict__ grids,
                                           const int* __restrict__ shx,
                                           const int* __restrict__ shy,
                                           float* __restrict__ ws) {
  __shared__ float sG[3 * 2401];
  __shared__ float sGr[100 * 49];
  int b = blockIdx.x;
  int t = threadIdx.x;
  for (int e = t; e < 3 * 2401; e += 256) sG[e] = 0.f;
  for (int e = t; e < 100 * 49; e += 256) sGr[e] = grids[b * 4900 + e];
  __syncthreads();
  if (t < 100) {
    int i = b * 100 + t;
    float num = ws[OFF_NUM + i], nrm = ws[OFF_NRM + i];
    float hsn = ws[OFF_HSN];
    float den = fmaxf(hsn * sqrtf(nrm), 1e-8f);
    float s = num / den;
    float s2 = s * s;
    int sig = shx[i] * 7 + shy[i];
    float* B0 = sG + sig * 49;
    const float* g = sGr + t * 49;
    for (int k = 0; k < 49; ++k) {
      if (g[k] != 0.f) {
        atomicAdd(&B0[k], 1.0f);
        atomicAdd(&B0[2401 + k], s);
        atomicAdd(&B0[4802 + k], s2);
      }
    }
  }
  __syncthreads();
  float* P = ws + OFF_GP + b * GSTRIDE;
  for (int e = t; e < 3 * 2401; e += 256) P[e] = sG[e];
}

// sum the 30 per-block partials into G
__global__ void __launch_bounds__(256) k_Gsum(float* __restrict__ ws) {
  int e = blockIdx.x * 256 + threadIdx.x;
  if (e >= 3 * 2401) return;
  float acc = 0.f;
  for (int b = 0; b < NGBLK; ++b) acc += ws[OFF_GP + b * GSTRIDE + e];
  ws[OFF_G + e] = acc;
}

// C_k[sx][gy][px] = sum_{sy,gx} wx(px,gx;sy) * G_k[sx,sy][gy,gx]
__global__ void __launch_bounds__(256) k_C(float* __restrict__ ws) {
  int tid = blockIdx.x * blockDim.x + threadIdx.x;
  if (tid >= 7 * 7 * 224) return;
  int px = tid % 224;
  int gy = (tid / 224) % 7;
  int sx = tid / (224 * 7);
  const float4* WT = (const float4*)(ws + OFF_WT);
  const float* G = ws + OFF_G;
  float c0 = 0.f, c1 = 0.f, c2 = 0.f;
  for (int sy = 0; sy < 7; ++sy) {
    float4 wt = WT[sy * 224 + px];
    int i0 = __float_as_int(wt.z), i1 = __float_as_int(wt.w);
    int base = (sx * 7 + sy) * 49 + gy * 7;
    c0 += wt.x * G[base + i0] + wt.y * G[base + i1];
    c1 += wt.x * G[2401 + base + i0] + wt.y * G[2401 + base + i1];
    c2 += wt.x * G[4802 + base + i0] + wt.y * G[4802 + base + i1];
  }
  float* C = ws + OFF_C;
  int cidx = (sx * 7 + gy) * 224 + px;
  C[cidx] = c0;
  C[10976 + cidx] = c1;
  C[21952 + cidx] = c2;
}

// final: S_k(py,px) = sum_{sx,gy} wy(py,gy;sx) * C_k[sx][gy][px]; closed-form Welford
__global__ void __launch_bounds__(256) k_out(const float* __restrict__ ws,
                                             float* __restrict__ out) {
  int tid = blockIdx.x * blockDim.x + threadIdx.x;
  if (tid >= 224 * 224) return;
  int px = tid % 224, py = tid / 224;
  const float4* WT = (const float4*)(ws + OFF_WT);
  const float* C = ws + OFF_C;
  float S0 = 0.f, S1 = 0.f, S2 = 0.f;
  for (int sx = 0; sx < 7; ++sx) {
    float4 wt = WT[sx * 224 + py];
    int i0 = __float_as_int(wt.z), i1 = __float_as_int(wt.w);
    int b0 = (sx * 7 + i0) * 224 + px;
    int b1 = (sx * 7 + i1) * 224 + px;
    S0 += wt.x * C[b0] + wt.y * C[b1];
    S1 += wt.x * C[10976 + b0] + wt.y * C[10976 + b1];
    S2 += wt.x * C[21952 + b0] + wt.y * C[21952 + b1];
  }
  float W = 1e-10f + S0;            // sow (includes init pseudo-weight)
  float R = S1 / W;                 // importance
  float U = S2 - S1 * S1 / W;       // weighted sum of squared deviations
  float unc = U / (W - 1.0f);
  out[tid] = R;
  out[224 * 224 + tid] = unc;
}

extern "C" void kernel_launch(void* const* d_in, const int* in_sizes, int n_in,
                              void* d_out, int out_size, void* d_ws, size_t ws_size,
                              hipStream_t stream) {
  const float* x     = (const float*)d_in[0];
  const float* Wenc  = (const float*)d_in[1];
  const float* grids = (const float*)d_in[2];
  const int*   shx   = (const int*)d_in[3];
  const int*   shy   = (const int*)d_in[4];
  float* out = (float*)d_out;
  float* ws  = (float*)d_ws;

  int vblocks = (7 * 3 * 224 * 7 + 255) / 256;          // 129
  k_initV<<<NF + 1 + vblocks, 256, 0, stream>>>(x, ws); // 277 blocks
  k_T<<<(NSIG * NF * 49 + 255) / 256, 256, 0, stream>>>(ws);
  k_H2<<<NHBLK, 256, 0, stream>>>(Wenc, grids, shx, shy, ws);
  k_G<<<NGBLK, 256, 0, stream>>>(grids, shx, shy, ws);
  k_Gsum<<<(3 * 2401 + 255) / 256, 256, 0, stream>>>(ws);
  k_C<<<(7 * 7 * 224 + 255) / 256, 256, 0, stream>>>(ws);
  k_out<<<(224 * 224 + 255) / 256, 256, 0, stream>>>(ws, out);
}